// Round 6
// baseline (299.893 us; speedup 1.0000x reference)
//
#include <hip/hip_runtime.h>
#include <hip/hip_bf16.h>

#define M_IN  32768
#define K_EMB 4096
#define D_DIM 256

// ---- ws layout (bytes) ----
#define WS_HWSQ   0         // float[4096]
#define WS_PACKS  16384     // u64[32768]
#define WS_COUNTS 278528    // int[4096]
#define WS_LOSS   294912    // float[64]

using f32x4  = __attribute__((ext_vector_type(4))) float;
using bf16x8 = __attribute__((ext_vector_type(8))) short;

static __device__ __forceinline__ unsigned short bf16_rtn(float f) {
    __hip_bfloat16 h = __float2bfloat16(f);  // RTN-even, same as all prior rounds
    return *reinterpret_cast<unsigned short*>(&h);
}

// ---------------- convw: W -> bf16 + 0.5||w||^2 + zero counts/loss ----------------
__global__ __launch_bounds__(256) void convw_kernel(const float* __restrict__ W,
                                                    unsigned short* __restrict__ Wb,
                                                    float* __restrict__ hwsq,
                                                    int* __restrict__ counts,
                                                    float* __restrict__ loss_slots)
{
    const int l = threadIdx.x & 63;
    const int k = blockIdx.x * 4 + (threadIdx.x >> 6);
    const int g = blockIdx.x * 256 + threadIdx.x;
    if (g < K_EMB) counts[g] = 0;
    if (g < 64)    loss_slots[g] = 0.f;
    float4 v = ((const float4*)(W + (size_t)k * D_DIM))[l];
    float s = v.x * v.x + v.y * v.y + v.z * v.z + v.w * v.w;
    union { unsigned short u[4]; uint2 q; } p;
    p.u[0] = bf16_rtn(v.x); p.u[1] = bf16_rtn(v.y);
    p.u[2] = bf16_rtn(v.z); p.u[3] = bf16_rtn(v.w);
    ((uint2*)(Wb + (size_t)k * D_DIM))[l] = p.q;
#pragma unroll
    for (int off = 32; off; off >>= 1) s += __shfl_xor(s, off);
    if (l == 0) hwsq[k] = 0.5f * s;
}

// ---------------- dist: B-in-registers, stream 16 m-tiles through dbuf LDS ----------------
// 256 blocks (1/CU). Block: nb (8 col-panels of 512) x mchunk (32 row-chunks of 1024).
// Wave w owns cols nb*512 + w*64: B-frags bq[kk 0..7][nj 0..3] resident in 128 VGPRs.
// Per m-tile (64 rows x K=256, 32KB bf16 LDS, 2 buffers):
//   T14 split: issue 8 f32x4 X-loads at iter top -> cvt+ds_write at iter end.
//   Swizzle: LDS granule h (16B) of row r holds data granule h ^ (r&7)
//   (bank = granule[0:2]*4 -> 16 frag-read lanes spread over 8 bank-quads, 2-way = free).
// XCD locality: mchunk % 8 == bid % 8 (round-robin dispatch heuristic) so the 8 blocks
// sharing X rows land on one XCD and re-read X from its L2.

#define EPILOGUE(ACC, HALF) {                                                  \
  _Pragma("unroll")                                                            \
  for (int mih = 0; mih < 2; mih++) {                                          \
    _Pragma("unroll")                                                          \
    for (int r = 0; r < 4; r++) {                                              \
      float bv = 3.4e38f; int bi = 0;                                          \
      _Pragma("unroll")                                                        \
      for (int nj = 0; nj < 4; nj++) {                                         \
        const float v = hw[nj] - ACC[mih][nj][r];                              \
        const int idx = nbase + nj*16 + (l & 15);                              \
        if (v < bv) { bv = v; bi = idx; }                                      \
      }                                                                        \
      unsigned long long pk =                                                  \
        ((unsigned long long)__float_as_uint(bv + 1.0f) << 32) | (unsigned)bi; \
      _Pragma("unroll")                                                        \
      for (int off = 1; off < 16; off <<= 1) {                                 \
        const unsigned long long o = __shfl_xor(pk, off);                      \
        if (o < pk) pk = o;                                                    \
      }                                                                        \
      if ((l & 15) == 0)                                                       \
        atomicMin(&packs[m0 + t*64 + (HALF)*32 + mih*16 + (l>>4)*4 + r], pk);  \
    }                                                                          \
  } }

__global__ __launch_bounds__(512, 2) void dist_kernel(const float* __restrict__ X,
                                                      const unsigned short* __restrict__ Wb,
                                                      const float* __restrict__ hwsq,
                                                      unsigned long long* __restrict__ packs)
{
    __shared__ char lds[65536];   // 2 x 32KB m-tile buffers

    const int tid = threadIdx.x;
    const int l = tid & 63;
    const int w = tid >> 6;

    const int bid    = blockIdx.x;
    const int nb     = (bid >> 3) & 7;
    const int mchunk = (bid & 7) + ((bid >> 6) << 3);   // mchunk%8 == bid%8
    const int m0     = mchunk * 1024;
    const int nbase  = nb * 512 + w * 64;

    // resident B-panel: 32 x bf16x8 = 128 VGPR
    bf16x8 bq[8][4];
#pragma unroll
    for (int kk = 0; kk < 8; kk++)
#pragma unroll
        for (int nj = 0; nj < 4; nj++) {
            const int row = nbase + nj * 16 + (l & 15);
            bq[kk][nj] = ((const bf16x8*)(Wb + (size_t)row * D_DIM))[kk * 4 + (l >> 4)];
        }

    float hw[4];
#pragma unroll
    for (int nj = 0; nj < 4; nj++) hw[nj] = hwsq[nbase + nj * 16 + (l & 15)];

    const int rl   = w * 2 + (l >> 5);          // staging row sub-index 0..15
    const int gsrc = (l & 31) ^ (rl & 7);       // pre-swizzled source granule
    const int Gb   = (w * 64 + l) * 16;         // linear LDS byte base (+ j*8192)

    // prologue: stage m-tile 0 into buf 0
    {
        float4 xr[8];
#pragma unroll
        for (int j = 0; j < 4; j++) {
            const float* src = X + (size_t)(m0 + j * 16 + rl) * D_DIM + gsrc * 8;
            xr[2 * j]     = ((const float4*)src)[0];
            xr[2 * j + 1] = ((const float4*)src)[1];
        }
#pragma unroll
        for (int j = 0; j < 4; j++) {
            union { unsigned short u[8]; bf16x8 v; } pw;
            pw.u[0] = bf16_rtn(xr[2*j].x);   pw.u[1] = bf16_rtn(xr[2*j].y);
            pw.u[2] = bf16_rtn(xr[2*j].z);   pw.u[3] = bf16_rtn(xr[2*j].w);
            pw.u[4] = bf16_rtn(xr[2*j+1].x); pw.u[5] = bf16_rtn(xr[2*j+1].y);
            pw.u[6] = bf16_rtn(xr[2*j+1].z); pw.u[7] = bf16_rtn(xr[2*j+1].w);
            *(bf16x8*)(&lds[j * 8192 + Gb]) = pw.v;
        }
    }

    for (int t = 0; t < 16; t++) {
        __syncthreads();   // buf[t&1] staged & visible; buf[(t+1)&1] fully consumed
        const char* buf  = &lds[(t & 1) * 32768];
        char*       nbuf = &lds[((t + 1) & 1) * 32768];

        // T14: issue next tile's global loads now; write to LDS at iter end
        float4 xr[8];
        if (t < 15) {
#pragma unroll
            for (int j = 0; j < 4; j++) {
                const float* src = X + (size_t)(m0 + (t + 1) * 64 + j * 16 + rl) * D_DIM + gsrc * 8;
                xr[2 * j]     = ((const float4*)src)[0];
                xr[2 * j + 1] = ((const float4*)src)[1];
            }
        }

        // ---- half 0: rows 0..31 ----
        f32x4 acc0[2][4];
#pragma unroll
        for (int mih = 0; mih < 2; mih++)
#pragma unroll
            for (int nj = 0; nj < 4; nj++) acc0[mih][nj] = (f32x4){0.f, 0.f, 0.f, 0.f};
#pragma unroll
        for (int kk = 0; kk < 8; kk++) {
            bf16x8 af[2];
#pragma unroll
            for (int mih = 0; mih < 2; mih++) {
                const int r = mih * 16 + (l & 15);
                const int perm = (kk * 4 + (l >> 4)) ^ (l & 7);
                af[mih] = *(const bf16x8*)(buf + r * 512 + perm * 16);
            }
            __builtin_amdgcn_s_setprio(1);
#pragma unroll
            for (int mih = 0; mih < 2; mih++)
#pragma unroll
                for (int nj = 0; nj < 4; nj++)
                    acc0[mih][nj] = __builtin_amdgcn_mfma_f32_16x16x32_bf16(
                        af[mih], bq[kk][nj], acc0[mih][nj], 0, 0, 0);
            __builtin_amdgcn_s_setprio(0);
        }
        EPILOGUE(acc0, 0)

        // ---- half 1: rows 32..63 ----
        f32x4 acc1[2][4];
#pragma unroll
        for (int mih = 0; mih < 2; mih++)
#pragma unroll
            for (int nj = 0; nj < 4; nj++) acc1[mih][nj] = (f32x4){0.f, 0.f, 0.f, 0.f};
#pragma unroll
        for (int kk = 0; kk < 8; kk++) {
            bf16x8 af[2];
#pragma unroll
            for (int mih = 0; mih < 2; mih++) {
                const int r = 32 + mih * 16 + (l & 15);
                const int perm = (kk * 4 + (l >> 4)) ^ (l & 7);
                af[mih] = *(const bf16x8*)(buf + r * 512 + perm * 16);
            }
            __builtin_amdgcn_s_setprio(1);
#pragma unroll
            for (int mih = 0; mih < 2; mih++)
#pragma unroll
                for (int nj = 0; nj < 4; nj++)
                    acc1[mih][nj] = __builtin_amdgcn_mfma_f32_16x16x32_bf16(
                        af[mih], bq[kk][nj], acc1[mih][nj], 0, 0, 0);
            __builtin_amdgcn_s_setprio(0);
        }

        // stage-write next tile (lands before next __syncthreads)
        if (t < 15) {
#pragma unroll
            for (int j = 0; j < 4; j++) {
                union { unsigned short u[8]; bf16x8 v; } pw;
                pw.u[0] = bf16_rtn(xr[2*j].x);   pw.u[1] = bf16_rtn(xr[2*j].y);
                pw.u[2] = bf16_rtn(xr[2*j].z);   pw.u[3] = bf16_rtn(xr[2*j].w);
                pw.u[4] = bf16_rtn(xr[2*j+1].x); pw.u[5] = bf16_rtn(xr[2*j+1].y);
                pw.u[6] = bf16_rtn(xr[2*j+1].z); pw.u[7] = bf16_rtn(xr[2*j+1].w);
                *(bf16x8*)(&nbuf[j * 8192 + Gb]) = pw.v;
            }
        }
        EPILOGUE(acc1, 1)
    }
}

// ---------------- merge: gather + counts + loss (xsq from X + 2*bv from packs) ----------------
__global__ __launch_bounds__(256) void merge_kernel(const float* __restrict__ X,
                                                    const float* __restrict__ W,
                                                    const unsigned long long* __restrict__ packs,
                                                    int* __restrict__ counts,
                                                    float* __restrict__ loss_slots,
                                                    char* __restrict__ outbase /* d_out+4 */)
{
    const int l   = threadIdx.x & 63;
    const int wv  = threadIdx.x >> 6;
    const int n0w = blockIdx.x * 64 + wv * 16;

    const unsigned long long pk = packs[n0w + (l & 15)];
    const int pkl = (int)(unsigned)(pk & 0xffffffffull);

    if (l < 16) atomicAdd(&counts[pkl], 1);

    // sum ||x||^2 over this wave's 16 rows (lane covers 4 cols per row)
    float xacc = 0.f;
#pragma unroll
    for (int r = 0; r < 16; r++) {
        const float4 xv = ((const float4*)(X + (size_t)(n0w + r) * D_DIM))[l];
        xacc = fmaf(xv.x, xv.x, fmaf(xv.y, xv.y, fmaf(xv.z, xv.z, fmaf(xv.w, xv.w, xacc))));
    }
    // ||x-w||^2 = ||x||^2 + 2*(0.5||w||^2 - x.w); bv lives in pack high bits (lanes 0-15)
    float comb = xacc + ((l < 16) ? 2.0f * (__uint_as_float((unsigned)(pk >> 32)) - 1.0f) : 0.f);
#pragma unroll
    for (int off = 32; off; off >>= 1) comb += __shfl_xor(comb, off);
    if (l == 0) atomicAdd(&loss_slots[(blockIdx.x * 4 + wv) & 63], comb);

    // gather W rows with 16 independent loads in flight
    float4 v[16];
#pragma unroll
    for (int r = 0; r < 16; r++) {
        const int idxr = __shfl(pkl, r);
        v[r] = ((const float4*)(W + (size_t)idxr * D_DIM))[l];
    }
    // aligned float4 stores into the 4B-misaligned out+1 rows via shift-by-one shuffle
#pragma unroll
    for (int r = 0; r < 16; r++) {
        char* bp = outbase + (size_t)(n0w + r) * 1024;
        const float nx = __shfl_down(v[r].x, 1);
        const float ny = __shfl_down(v[r].y, 1);
        const float nz = __shfl_down(v[r].z, 1);
        if (l < 63)
            *(float4*)(bp + 12 + 16 * l) = make_float4(v[r].w, nx, ny, nz);
        if (l == 0) {
            ((float*)bp)[0] = v[r].x; ((float*)bp)[1] = v[r].y; ((float*)bp)[2] = v[r].z;
        }
        if (l == 63) ((float*)bp)[255] = v[r].w;
    }
}

// ---------------- finalize ----------------
__global__ __launch_bounds__(256) void finalize_kernel(const int* __restrict__ counts,
                                                       const float* __restrict__ loss_slots,
                                                       float* __restrict__ out)
{
    const int tid = threadIdx.x;
    float ent = 0.f;
    for (int k = tid; k < K_EMB; k += 256) {
        const float p = (float)counts[k] * (1.0f / (float)M_IN);
        ent += p * logf(p + 1e-10f);
    }
#pragma unroll
    for (int off = 32; off; off >>= 1) ent += __shfl_xor(ent, off);
    __shared__ float red[4];
    if ((tid & 63) == 0) red[tid >> 6] = ent;
    __syncthreads();
    if (tid == 0) {
        const float e = red[0] + red[1] + red[2] + red[3];
        float ls = 0.f;
        for (int i = 0; i < 64; i++) ls += loss_slots[i];
        out[0] = 1.25f * ls / ((float)M_IN * (float)D_DIM);
        out[1 + (size_t)M_IN * D_DIM] = expf(-e);
    }
}

extern "C" void kernel_launch(void* const* d_in, const int* in_sizes, int n_in,
                              void* d_out, int out_size, void* d_ws, size_t ws_size,
                              hipStream_t stream)
{
    const float* X = (const float*)d_in[0];
    const float* W = (const float*)d_in[1];
    float* out = (float*)d_out;
    char*  ws  = (char*)d_ws;

    float* hwsq               = (float*)(ws + WS_HWSQ);
    unsigned long long* packs = (unsigned long long*)(ws + WS_PACKS);
    int*   counts             = (int*)(ws + WS_COUNTS);
    float* loss_slots         = (float*)(ws + WS_LOSS);

    // Wb (2MB bf16) lives inside d_out's quantized region (overwritten by merge later)
    unsigned short* Wb = (unsigned short*)((char*)d_out + 4096);

    hipMemsetAsync(packs, 0xFF, 262144, stream);   // packs = +inf

    convw_kernel<<<K_EMB / 4, 256, 0, stream>>>(W, Wb, hwsq, counts, loss_slots);
    dist_kernel<<<256, 512, 0, stream>>>(X, Wb, hwsq, packs);
    merge_kernel<<<M_IN / 64, 256, 0, stream>>>(X, W, packs, counts, loss_slots,
                                                (char*)d_out + 4);
    finalize_kernel<<<1, 256, 0, stream>>>(counts, loss_slots, out);
}

// Round 7
// 214.701 us; speedup vs baseline: 1.3968x; 1.3968x over previous
//
#include <hip/hip_runtime.h>
#include <hip/hip_bf16.h>

#define M_IN  32768
#define K_EMB 4096
#define D_DIM 256
#define WROW  288     // padded Wb row: 256 bf16 data + [ -0.5*||w||^2, 0 x31 ]
#define MT    32      // rows per streamed m-tile
#define NITER 32      // m-tiles per block (1024 rows/block)
#define PANELS 16     // 4096 cols / 256 cols-per-block

// ---- ws layout (bytes) ----
#define WS_PACKS 0        // u64[32768]
#define WS_LOSS  262144   // float[64]

using f32x4  = __attribute__((ext_vector_type(4))) float;
using bf16x8 = __attribute__((ext_vector_type(8))) short;

static __device__ __forceinline__ unsigned short bf16_rtn(float f) {
    __hip_bfloat16 h = __float2bfloat16(f);  // RTN-even, same as all prior rounds
    return *reinterpret_cast<unsigned short*>(&h);
}

// ---------------- convw: W -> padded bf16 rows (incl. -0.5||w||^2 at col 256) ----------------
__global__ __launch_bounds__(256) void convw_kernel(const float* __restrict__ W,
                                                    unsigned short* __restrict__ Wb,
                                                    float* __restrict__ loss_slots)
{
    const int l = threadIdx.x & 63;
    const int k = blockIdx.x * 4 + (threadIdx.x >> 6);
    const int g = blockIdx.x * 256 + threadIdx.x;
    if (g < 64) loss_slots[g] = 0.f;
    float4 v = ((const float4*)(W + (size_t)k * D_DIM))[l];
    float s = v.x * v.x + v.y * v.y + v.z * v.z + v.w * v.w;
    union { unsigned short u[4]; uint2 q; } p;
    p.u[0] = bf16_rtn(v.x); p.u[1] = bf16_rtn(v.y);
    p.u[2] = bf16_rtn(v.z); p.u[3] = bf16_rtn(v.w);
    ((uint2*)(Wb + (size_t)k * WROW))[l] = p.q;        // cols 4l..4l+3
#pragma unroll
    for (int off = 32; off; off >>= 1) s += __shfl_xor(s, off);
    if (l < 8) {                                        // pad cols 256..287
        uint2 z = make_uint2(0u, 0u);
        if (l == 0) z.x = (unsigned)bf16_rtn(-0.5f * s);  // elem0 = -hw, elem1 = 0
        ((uint2*)(Wb + (size_t)k * WROW + 256))[l] = z;
    }
}

// ---------------- dist: B-in-registers, swapped-operand MFMA, lane-local argmax ----------------
// 512 blocks (2/CU), 4 waves. Block = col-panel p (256 cols) x row-chunk mc (1024 rows).
// Wave owns 64 W-cols: bq[9][4] resident (144 VGPR; kk=8 is the hw-pad block).
// mfma(A=bq, B=xf): C col = l&15 = X-row, C row = (l>>4)*4+reg = W-col -> per-X-row argmax
// is a lane-local scan of 16 regs + shfl_xor(16,32) over the 4 lanes sharing the row.
// LDS m-tile [32 rows][256 k] bf16, granule-XOR swizzle g ^= (row&7), dbuf 2x16KB.
// In-block merge via mlds[2][32][4] -> 32 atomicMin per tile (524K total, round-5-proven).

#define ISSUE(MTI) { \
    const float* rp_ = X + (size_t)(m0 + (MTI) * MT + srow) * D_DIM; \
    _Pragma("unroll") \
    for (int j_ = 0; j_ < 4; j_++) { \
        xr[2*j_]   = ((const float4*)(rp_ + (sgd + 8*j_) * 8))[0]; \
        xr[2*j_+1] = ((const float4*)(rp_ + (sgd + 8*j_) * 8))[1]; \
    } }

#define WRITE(BUF) { \
    char* b_ = lds + (BUF) * 16384 + srow * 512; \
    _Pragma("unroll") \
    for (int j_ = 0; j_ < 4; j_++) { \
        union { unsigned short u[8]; bf16x8 v; } pw_; \
        pw_.u[0] = bf16_rtn(xr[2*j_].x);   pw_.u[1] = bf16_rtn(xr[2*j_].y); \
        pw_.u[2] = bf16_rtn(xr[2*j_].z);   pw_.u[3] = bf16_rtn(xr[2*j_].w); \
        pw_.u[4] = bf16_rtn(xr[2*j_+1].x); pw_.u[5] = bf16_rtn(xr[2*j_+1].y); \
        pw_.u[6] = bf16_rtn(xr[2*j_+1].z); pw_.u[7] = bf16_rtn(xr[2*j_+1].w); \
        *(bf16x8*)(b_ + (((sgd + 8*j_) ^ (srow & 7)) << 4)) = pw_.v; \
    } }

__global__ __launch_bounds__(256, 2) void dist_kernel(const float* __restrict__ X,
                                                      const unsigned short* __restrict__ Wb,
                                                      unsigned long long* __restrict__ packs)
{
    __shared__ char lds[32768];                       // 2 x 16KB m-tile buffers
    __shared__ unsigned long long mlds[2][MT][4];     // per-tile cross-wave merge (dbuf)

    const int tid = threadIdx.x;
    const int l = tid & 63;
    const int w = tid >> 6;

    const int p  = blockIdx.x & (PANELS - 1);
    const int mc = blockIdx.x / PANELS;
    const int m0 = mc * (MT * NITER);
    const int nbase = p * 256 + w * 64;

    // resident W-panel: 9 kk x 4 nj frags (A-operand layout: row = l&15, k-chunk = l>>4)
    bf16x8 bq[9][4];
#pragma unroll
    for (int kk = 0; kk < 9; kk++)
#pragma unroll
        for (int nj = 0; nj < 4; nj++) {
            const int row = nbase + nj * 16 + (l & 15);
            bq[kk][nj] = ((const bf16x8*)(Wb + (size_t)row * WROW))[kk * 4 + (l >> 4)];
        }

    // x-pad B-frag: every X-row's pad block is [1, 0...]; chunk 0 lives in lanes l<16
    bf16x8 xpad = (bf16x8){0,0,0,0,0,0,0,0};
    if (l < 16) xpad[0] = (short)0x3F80;   // bf16(1.0)

    const int srow = tid >> 3;   // staging row 0..31
    const int sgd  = tid & 7;    // staging granule low bits

    float4 xr[8];
    ISSUE(0)
    WRITE(0)
    __syncthreads();

    for (int mt = 0; mt < NITER; ++mt) {
        if (mt + 1 < NITER) ISSUE(mt + 1)                 // T14: loads fly under compute

        if (mt > 0 && tid < MT) {                         // merge+flush previous tile
            const int par = (mt - 1) & 1;
            unsigned long long pm = mlds[par][tid][0];
#pragma unroll
            for (int q = 1; q < 4; q++) {
                const unsigned long long o = mlds[par][tid][q];
                if (o < pm) pm = o;
            }
            atomicMin(&packs[m0 + (mt - 1) * MT + tid], pm);
        }

        const char* buf = lds + (mt & 1) * 16384;
        f32x4 acc[2][4];
#pragma unroll
        for (int mi = 0; mi < 2; mi++)
#pragma unroll
            for (int nj = 0; nj < 4; nj++) acc[mi][nj] = (f32x4){0.f, 0.f, 0.f, 0.f};

#pragma unroll
        for (int kk = 0; kk < 8; kk++) {
            bf16x8 xf[2];
#pragma unroll
            for (int mi = 0; mi < 2; mi++)
                xf[mi] = *(const bf16x8*)(buf + (mi * 16 + (l & 15)) * 512
                          + (((kk * 4 + (l >> 4)) ^ (l & 7)) << 4));
#pragma unroll
            for (int mi = 0; mi < 2; mi++)
#pragma unroll
                for (int nj = 0; nj < 4; nj++)
                    acc[mi][nj] = __builtin_amdgcn_mfma_f32_16x16x32_bf16(
                        bq[kk][nj], xf[mi], acc[mi][nj], 0, 0, 0);
        }
        // pad MFMA: adds (-0.5||w||^2) so acc = dot - hw  (argmin dist == argmax acc)
#pragma unroll
        for (int mi = 0; mi < 2; mi++)
#pragma unroll
            for (int nj = 0; nj < 4; nj++)
                acc[mi][nj] = __builtin_amdgcn_mfma_f32_16x16x32_bf16(
                    bq[8][nj], xpad, acc[mi][nj], 0, 0, 0);

        if (mt + 1 < NITER) WRITE((mt + 1) & 1)           // lands before loop-end barrier

        // epilogue: lane-local argmax over 16 candidates, 4-lane reduce, mlds stash
#pragma unroll
        for (int mi = 0; mi < 2; mi++) {
            float best = acc[mi][0][0];
            int bo = 0;                                   // offset = nj*16 + r (ascending col)
#pragma unroll
            for (int nj = 0; nj < 4; nj++)
#pragma unroll
                for (int r = 0; r < 4; r++) {
                    if (nj == 0 && r == 0) continue;
                    const float v = acc[mi][nj][r];
                    if (v > best) { best = v; bo = nj * 16 + r; }  // strict > keeps lowest col
                }
            const int col = nbase + (l >> 4) * 4 + bo;
            unsigned long long pk =
                ((unsigned long long)__float_as_uint(1.0f - best) << 32) | (unsigned)col;
            unsigned long long o = __shfl_xor(pk, 16); if (o < pk) pk = o;
            o = __shfl_xor(pk, 32); if (o < pk) pk = o;
            if (l < 16) mlds[mt & 1][mi * 16 + l][w] = pk;
        }
        __syncthreads();
    }

    if (tid < MT) {                                       // flush last tile
        const int par = (NITER - 1) & 1;
        unsigned long long pm = mlds[par][tid][0];
#pragma unroll
        for (int q = 1; q < 4; q++) {
            const unsigned long long o = mlds[par][tid][q];
            if (o < pm) pm = o;
        }
        atomicMin(&packs[m0 + (NITER - 1) * MT + tid], pm);
    }
}

// ---------------- merge: gather W rows + loss (no counts here) ----------------
__global__ __launch_bounds__(256) void merge_kernel(const float* __restrict__ X,
                                                    const float* __restrict__ W,
                                                    const unsigned long long* __restrict__ packs,
                                                    float* __restrict__ loss_slots,
                                                    char* __restrict__ outbase /* d_out+4 */)
{
    const int l   = threadIdx.x & 63;
    const int wv  = threadIdx.x >> 6;
    const int n0w = blockIdx.x * 64 + wv * 16;

    const unsigned long long pk = packs[n0w + (l & 15)];
    const int pkl = (int)(unsigned)(pk & 0xffffffffull);

    // sum ||x||^2 over this wave's 16 rows
    float xacc = 0.f;
#pragma unroll
    for (int r = 0; r < 16; r++) {
        const float4 xv = ((const float4*)(X + (size_t)(n0w + r) * D_DIM))[l];
        xacc = fmaf(xv.x, xv.x, fmaf(xv.y, xv.y, fmaf(xv.z, xv.z, fmaf(xv.w, xv.w, xacc))));
    }
    // ||x-w||^2 = ||x||^2 + 2*proxy; proxy = unpack(pk) - 1.0 (lanes 0-15 hold valid packs)
    float comb = xacc + ((l < 16) ? 2.0f * (__uint_as_float((unsigned)(pk >> 32)) - 1.0f) : 0.f);
#pragma unroll
    for (int off = 32; off; off >>= 1) comb += __shfl_xor(comb, off);
    if (l == 0) atomicAdd(&loss_slots[(blockIdx.x * 4 + wv) & 63], comb);

    // gather W rows, 16 independent loads in flight
    float4 v[16];
#pragma unroll
    for (int r = 0; r < 16; r++) {
        const int idxr = __shfl(pkl, r);
        v[r] = ((const float4*)(W + (size_t)idxr * D_DIM))[l];
    }
    // aligned float4 stores into the 4B-misaligned out+1 rows via shift-by-one shuffle
#pragma unroll
    for (int r = 0; r < 16; r++) {
        char* bp = outbase + (size_t)(n0w + r) * 1024;
        const float nx = __shfl_down(v[r].x, 1);
        const float ny = __shfl_down(v[r].y, 1);
        const float nz = __shfl_down(v[r].z, 1);
        if (l < 63)
            *(float4*)(bp + 12 + 16 * l) = make_float4(v[r].w, nx, ny, nz);
        if (l == 0) {
            ((float*)bp)[0] = v[r].x; ((float*)bp)[1] = v[r].y; ((float*)bp)[2] = v[r].z;
        }
        if (l == 63) ((float*)bp)[255] = v[r].w;
    }
}

// ---------------- finalize: LDS histogram from packs + entropy + loss ----------------
__global__ __launch_bounds__(256) void finalize_kernel(const unsigned long long* __restrict__ packs,
                                                       const float* __restrict__ loss_slots,
                                                       float* __restrict__ out)
{
    __shared__ int hist[K_EMB];
    const int tid = threadIdx.x;
    for (int k = tid; k < K_EMB; k += 256) hist[k] = 0;
    __syncthreads();
    for (int n = tid; n < M_IN; n += 256)
        atomicAdd(&hist[(int)(unsigned)(packs[n] & 0xffffffffull)], 1);
    __syncthreads();
    float ent = 0.f;
    for (int k = tid; k < K_EMB; k += 256) {
        const float p = (float)hist[k] * (1.0f / (float)M_IN);
        ent += p * logf(p + 1e-10f);
    }
#pragma unroll
    for (int off = 32; off; off >>= 1) ent += __shfl_xor(ent, off);
    __shared__ float red[4];
    if ((tid & 63) == 0) red[tid >> 6] = ent;
    __syncthreads();
    if (tid == 0) {
        const float e = red[0] + red[1] + red[2] + red[3];
        float ls = 0.f;
        for (int i = 0; i < 64; i++) ls += loss_slots[i];
        out[0] = 1.25f * ls / ((float)M_IN * (float)D_DIM);
        out[1 + (size_t)M_IN * D_DIM] = expf(-e);
    }
}

extern "C" void kernel_launch(void* const* d_in, const int* in_sizes, int n_in,
                              void* d_out, int out_size, void* d_ws, size_t ws_size,
                              hipStream_t stream)
{
    const float* X = (const float*)d_in[0];
    const float* W = (const float*)d_in[1];
    float* out = (float*)d_out;
    char*  ws  = (char*)d_ws;

    unsigned long long* packs = (unsigned long long*)(ws + WS_PACKS);
    float* loss_slots         = (float*)(ws + WS_LOSS);

    // padded Wb (2.36 MB) inside d_out's quantized region (overwritten by merge afterwards)
    unsigned short* Wb = (unsigned short*)((char*)d_out + 4096);

    hipMemsetAsync(packs, 0xFF, 262144, stream);   // packs = +inf

    convw_kernel<<<K_EMB / 4, 256, 0, stream>>>(W, Wb, loss_slots);
    dist_kernel<<<PANELS * (M_IN / (MT * NITER)), 256, 0, stream>>>(X, Wb, packs);
    merge_kernel<<<M_IN / 64, 256, 0, stream>>>(X, W, packs, loss_slots, (char*)d_out + 4);
    finalize_kernel<<<1, 256, 0, stream>>>(packs, loss_slots, out);
}